// Round 2
// baseline (920.190 us; speedup 1.0000x reference)
//
#include <hip/hip_runtime.h>

// Fused causal MHA forward, fp32 baseline.
// B=2, S=2048, E=1024, H=16, D=64.
// Structure: 3x QKV projection GEMM -> flash attention -> output GEMM.
// Workspace: q (16MB) + k (16MB) in d_ws; v lives in d_out (dead before the
// final GEMM overwrites it); ctx aliases q (disjoint per-block read->write).

#define SEQ   2048
#define EMBED 1024
#define NHEADS 16
#define HDIM  64
#define MROWS 4096  // B*S

// ---------------------------------------------------------------------------
// C[M,N] = A[M,K] @ W[N,K]^T + bias[N]   (torch Linear semantics)
// 64x64 tile, K-step 16, 256 threads, 4x4 outputs/thread.
// LDS layout [kk][row] padded to 68 so float4 reads stay 16B-aligned.
// ---------------------------------------------------------------------------
__global__ __launch_bounds__(256) void gemm_nt_bias(
    const float* __restrict__ A, const float* __restrict__ W,
    const float* __restrict__ bias, float* __restrict__ C,
    int M, int N, int K)
{
    __shared__ __align__(16) float As[16][68];
    __shared__ __align__(16) float Bs[16][68];
    const int tid = threadIdx.x;
    const int bm = blockIdx.x * 64;
    const int bn = blockIdx.y * 64;
    const int lr = tid >> 2;          // 0..63  (tile row loaded by this thread)
    const int lk = (tid & 3) << 2;    // 0,4,8,12 (k offset, float4)
    const int tm = (tid >> 4) << 2;   // 0..60 output row group
    const int tn = (tid & 15) << 2;   // 0..60 output col group

    const float* Ap = A + (size_t)(bm + lr) * K + lk;
    const float* Wp = W + (size_t)(bn + lr) * K + lk;

    float acc[4][4] = {{0.f}};

    for (int k0 = 0; k0 < K; k0 += 16) {
        const float4 av = *(const float4*)(Ap + k0);
        const float4 wv = *(const float4*)(Wp + k0);
        __syncthreads();              // previous iteration's reads complete
        As[lk+0][lr] = av.x; As[lk+1][lr] = av.y; As[lk+2][lr] = av.z; As[lk+3][lr] = av.w;
        Bs[lk+0][lr] = wv.x; Bs[lk+1][lr] = wv.y; Bs[lk+2][lr] = wv.z; Bs[lk+3][lr] = wv.w;
        __syncthreads();
        #pragma unroll
        for (int kk = 0; kk < 16; ++kk) {
            const float4 a = *(const float4*)&As[kk][tm];
            const float4 b = *(const float4*)&Bs[kk][tn];
            const float a4[4] = {a.x, a.y, a.z, a.w};
            const float b4[4] = {b.x, b.y, b.z, b.w};
            #pragma unroll
            for (int i = 0; i < 4; ++i)
                #pragma unroll
                for (int j = 0; j < 4; ++j)
                    acc[i][j] = fmaf(a4[i], b4[j], acc[i][j]);
        }
    }

    #pragma unroll
    for (int i = 0; i < 4; ++i) {
        float4 r;
        r.x = acc[i][0] + bias[bn+tn+0];
        r.y = acc[i][1] + bias[bn+tn+1];
        r.z = acc[i][2] + bias[bn+tn+2];
        r.w = acc[i][3] + bias[bn+tn+3];
        *(float4*)(C + (size_t)(bm+tm+i)*N + bn + tn) = r;
    }
}

// ---------------------------------------------------------------------------
// Flash-style causal attention. One block per (b*H+h, q-tile of 64 rows).
// Q/K/V layout: [B, S, H*D] (projection output), head slice at h*HDIM.
// Online softmax; scores and PV both as 4x4-register-blocked LDS GEMMs.
// KVs buffer is time-shared: K^T for scores, then V for PV (keeps LDS <64KB).
// ---------------------------------------------------------------------------
__global__ __launch_bounds__(256) void attn_causal(
    const float* __restrict__ Qg, const float* __restrict__ Kg,
    const float* __restrict__ Vg, float* __restrict__ Og)
{
    __shared__ __align__(16) float Qt[64][68];   // [d][qrow]
    __shared__ __align__(16) float KVs[64][68];  // K phase: [d][krow]; V phase: [krow][d]
    __shared__ __align__(16) float Pt[64][68];   // [kcol][qrow]

    const int tid = threadIdx.x;
    const int bh = blockIdx.x;
    const int b = bh >> 4, h = bh & 15;
    const int qt = blockIdx.y;

    const size_t base = (size_t)b * SEQ * EMBED + (size_t)h * HDIM;

    const int lr = tid >> 2;          // row loaded by this thread
    const int d0 = (tid & 3) << 4;    // 16-float chunk of the 64-dim head

    // Q tile -> LDS, transposed to [d][qrow]
    {
        const float* qp = Qg + base + (size_t)(qt*64 + lr) * EMBED + d0;
        #pragma unroll
        for (int i = 0; i < 16; i += 4) {
            const float4 q4 = *(const float4*)(qp + i);
            Qt[d0+i+0][lr] = q4.x; Qt[d0+i+1][lr] = q4.y;
            Qt[d0+i+2][lr] = q4.z; Qt[d0+i+3][lr] = q4.w;
        }
    }

    const int tm = (tid >> 4) << 2;   // q-row group (4 rows)
    const int tn = (tid & 15) << 2;   // k-col group / head-dim group

    float m_i[4], l_i[4], o[4][4];
    #pragma unroll
    for (int i = 0; i < 4; ++i) {
        m_i[i] = -1e30f; l_i[i] = 0.f;
        #pragma unroll
        for (int j = 0; j < 4; ++j) o[i][j] = 0.f;
    }

    for (int kt = 0; kt <= qt; ++kt) {
        __syncthreads();  // prev PV reads of KVs/Pt done; (iter0: Qt store ordering)
        {   // K tile -> LDS transposed [d][krow]
            const float* kp = Kg + base + (size_t)(kt*64 + lr) * EMBED + d0;
            #pragma unroll
            for (int i = 0; i < 16; i += 4) {
                const float4 k4 = *(const float4*)(kp + i);
                KVs[d0+i+0][lr] = k4.x; KVs[d0+i+1][lr] = k4.y;
                KVs[d0+i+2][lr] = k4.z; KVs[d0+i+3][lr] = k4.w;
            }
        }
        __syncthreads();

        // scores sc[i][j] = sum_d Q[tm+i][d] * K[tn+j][d]
        float sc[4][4] = {{0.f}};
        #pragma unroll 8
        for (int kk = 0; kk < 64; ++kk) {
            const float4 a = *(const float4*)&Qt[kk][tm];
            const float4 bb = *(const float4*)&KVs[kk][tn];
            const float a4[4] = {a.x,a.y,a.z,a.w};
            const float b4[4] = {bb.x,bb.y,bb.z,bb.w};
            #pragma unroll
            for (int i = 0; i < 4; ++i)
                #pragma unroll
                for (int j = 0; j < 4; ++j)
                    sc[i][j] = fmaf(a4[i], b4[j], sc[i][j]);
        }

        const bool diag = (kt == qt);
        #pragma unroll
        for (int i = 0; i < 4; ++i)
            #pragma unroll
            for (int j = 0; j < 4; ++j) {
                float s = sc[i][j] * 0.125f;             // 1/sqrt(64)
                if (diag && (tn + j > tm + i)) s = -1e30f;  // causal mask
                sc[i][j] = s;
            }

        // online softmax; 16 consecutive lanes share a q-row
        #pragma unroll
        for (int i = 0; i < 4; ++i) {
            float mx = fmaxf(fmaxf(sc[i][0], sc[i][1]), fmaxf(sc[i][2], sc[i][3]));
            mx = fmaxf(mx, __shfl_xor(mx, 1));
            mx = fmaxf(mx, __shfl_xor(mx, 2));
            mx = fmaxf(mx, __shfl_xor(mx, 4));
            mx = fmaxf(mx, __shfl_xor(mx, 8));
            const float mnew = fmaxf(m_i[i], mx);
            const float corr = __expf(m_i[i] - mnew);
            float ps = 0.f;
            #pragma unroll
            for (int j = 0; j < 4; ++j) {
                const float p = __expf(sc[i][j] - mnew);
                Pt[tn+j][tm+i] = p;
                ps += p;
            }
            ps += __shfl_xor(ps, 1);
            ps += __shfl_xor(ps, 2);
            ps += __shfl_xor(ps, 4);
            ps += __shfl_xor(ps, 8);
            l_i[i] = l_i[i] * corr + ps;
            m_i[i] = mnew;
            #pragma unroll
            for (int j = 0; j < 4; ++j) o[i][j] *= corr;
        }

        __syncthreads();  // Pt written; K reads of KVs done

        {   // V tile -> LDS row-major [krow][d] (overwrites K^T)
            const float* vp = Vg + base + (size_t)(kt*64 + lr) * EMBED + d0;
            #pragma unroll
            for (int i = 0; i < 16; i += 4)
                *(float4*)&KVs[lr][d0+i] = *(const float4*)(vp + i);
        }
        __syncthreads();  // V ready

        // o[i][j] += sum_c P[tm+i][c] * V[c][tn+j]
        #pragma unroll 8
        for (int c = 0; c < 64; ++c) {
            const float4 a = *(const float4*)&Pt[c][tm];
            const float4 bb = *(const float4*)&KVs[c][tn];
            const float a4[4] = {a.x,a.y,a.z,a.w};
            const float b4[4] = {bb.x,bb.y,bb.z,bb.w};
            #pragma unroll
            for (int i = 0; i < 4; ++i)
                #pragma unroll
                for (int j = 0; j < 4; ++j)
                    o[i][j] = fmaf(a4[i], b4[j], o[i][j]);
        }
    }

    // normalize + write ctx[b, s, h*D + d]
    #pragma unroll
    for (int i = 0; i < 4; ++i) {
        const float inv = 1.f / l_i[i];
        float4 r;
        r.x = o[i][0]*inv; r.y = o[i][1]*inv; r.z = o[i][2]*inv; r.w = o[i][3]*inv;
        *(float4*)(Og + base + (size_t)(qt*64 + tm + i) * EMBED + tn) = r;
    }
}

// ---------------------------------------------------------------------------
extern "C" void kernel_launch(void* const* d_in, const int* in_sizes, int n_in,
                              void* d_out, int out_size, void* d_ws, size_t ws_size,
                              hipStream_t stream)
{
    const float* x  = (const float*)d_in[0];
    const float* Wq = (const float*)d_in[1];
    const float* bq = (const float*)d_in[2];
    const float* Wk = (const float*)d_in[3];
    const float* bk = (const float*)d_in[4];
    const float* Wv = (const float*)d_in[5];
    const float* bv = (const float*)d_in[6];
    const float* Wo = (const float*)d_in[7];
    const float* bo = (const float*)d_in[8];
    float* out = (float*)d_out;

    const size_t BUF = (size_t)MROWS * EMBED;      // 4M floats = 16 MB
    if (ws_size < 2 * BUF * sizeof(float)) return; // refuse OOB ws writes

    float* q = (float*)d_ws;                       // ws[0:16MB)
    float* k = q + BUF;                            // ws[16MB:32MB)
    // v lives in d_out: it is dead by the time the final GEMM writes out.
    float* v = out;
    // ctx aliases q: block (b,h,qt) caches its q rows in LDS up front; only
    // that block reads q[b, qt-rows, h-slice], and its ctx write targets
    // exactly that disjoint region after the reads. No cross-block overlap.
    float* ctx = q;

    dim3 gg(MROWS/64, EMBED/64);
    gemm_nt_bias<<<gg, 256, 0, stream>>>(x, Wq, bq, q, MROWS, EMBED, EMBED);
    gemm_nt_bias<<<gg, 256, 0, stream>>>(x, Wk, bk, k, MROWS, EMBED, EMBED);
    gemm_nt_bias<<<gg, 256, 0, stream>>>(x, Wv, bv, v, MROWS, EMBED, EMBED);
    attn_causal<<<dim3(NHEADS*2, SEQ/64), 256, 0, stream>>>(q, k, v, ctx);
    gemm_nt_bias<<<gg, 256, 0, stream>>>(ctx, Wo, bo, out, MROWS, EMBED, EMBED);
}

// Round 4
// 602.812 us; speedup vs baseline: 1.5265x; 1.5265x over previous
//
#include <hip/hip_runtime.h>

// Fused causal MHA forward. B=2, S=2048, E=1024, H=16, D=64.
// R3/R4: projection GEMMs on MFMA bf16x3 (A=Ah+Al split, 3 MFMA products;
// residual ~2^-16 relative). fp32->bf16 hi/lo conversion happens in-kernel
// during LDS staging so workspace stays at the proven-safe 32 MB.
// Attention kernel unchanged from the passing R2 fp32 version.

#define SEQ   2048
#define EMBED 1024
#define NHEADS 16
#define HDIM  64
#define MROWS 4096  // B*S

typedef __attribute__((ext_vector_type(8))) short bf16x8;
typedef __attribute__((ext_vector_type(4))) float f32x4;

__device__ __forceinline__ unsigned short bf16_rne(float x) {
    unsigned u = __builtin_bit_cast(unsigned, x);
    unsigned r = u + 0x7fffu + ((u >> 16) & 1u);   // round-to-nearest-even
    return (unsigned short)(r >> 16);
}
__device__ __forceinline__ float bf16_to_f32(unsigned short h) {
    return __builtin_bit_cast(float, (unsigned)h << 16);
}

// ---------------------------------------------------------------------------
// C[M,N] = A[M,K] @ W[N,K]^T + bias[N], fp32 in/out, bf16x3 MFMA compute.
// 128x128 tile, BK=32, 256 threads (4 waves, 2x2 wave grid, 64x64 per wave).
// LDS: [kchunk 0..3][row 0..127][8 bf16] per matrix per hi/lo -> 4 x 8 KB.
// mfma_f32_16x16x32_bf16 fragments: A lane l holds A[l&15][(l>>4)*8 + j];
// B lane l holds B[(l>>4)*8 + j][l&15] = W[l&15][k...] (NT GEMM: identical
// load pattern for both operands). C/D: col=lane&15, row=(lane>>4)*4+reg.
// ---------------------------------------------------------------------------
__global__ __launch_bounds__(256) void gemm_nt_bf16x3(
    const float* __restrict__ A, const float* __restrict__ W,
    const float* __restrict__ bias, float* __restrict__ C,
    int M, int N, int K)
{
    __shared__ __align__(16) unsigned short Ah[4096];
    __shared__ __align__(16) unsigned short Al[4096];
    __shared__ __align__(16) unsigned short Wh[4096];
    __shared__ __align__(16) unsigned short Wl[4096];

    const int tid = threadIdx.x;
    const int bm = blockIdx.x * 128;
    const int bn = blockIdx.y * 128;

    // staging: thread -> (row, 16-wide k-slice)
    const int sr  = tid >> 1;            // 0..127
    const int sk  = (tid & 1) * 16;      // 0 or 16
    const int kc0 = (tid & 1) * 2;       // first kchunk this thread fills

    const float* Ap = A + (size_t)(bm + sr) * K + sk;
    const float* Wp = W + (size_t)(bn + sr) * K + sk;

    // compute: wave/lane -> fragment coords
    const int lane = tid & 63;
    const int wv = tid >> 6;
    const int wm = (wv >> 1) * 64;
    const int wn = (wv & 1) * 64;
    const int fr = lane & 15;            // frag row (A) / col (B)
    const int fk = lane >> 4;            // k-chunk

    f32x4 acc[4][4];
    #pragma unroll
    for (int i = 0; i < 4; ++i)
        #pragma unroll
        for (int j = 0; j < 4; ++j)
            acc[i][j] = (f32x4){0.f, 0.f, 0.f, 0.f};

    float4 ra[4], rw[4];
    #pragma unroll
    for (int i = 0; i < 4; ++i) {         // prologue: K-step 0
        ra[i] = *(const float4*)(Ap + i * 4);
        rw[i] = *(const float4*)(Wp + i * 4);
    }

    for (int k0 = 0; k0 < K; k0 += 32) {
        __syncthreads();                  // prior MFMA reads of LDS complete

        // ---- convert current regs -> hi/lo bf16, write LDS ----
        #pragma unroll
        for (int s = 0; s < 2; ++s) {     // slot s covers kchunk kc0+s
            const float ea[8] = { ra[2*s].x, ra[2*s].y, ra[2*s].z, ra[2*s].w,
                                  ra[2*s+1].x, ra[2*s+1].y, ra[2*s+1].z, ra[2*s+1].w };
            const float ew[8] = { rw[2*s].x, rw[2*s].y, rw[2*s].z, rw[2*s].w,
                                  rw[2*s+1].x, rw[2*s+1].y, rw[2*s+1].z, rw[2*s+1].w };
            bf16x8 ahv, alv, whv, wlv;
            #pragma unroll
            for (int j = 0; j < 8; ++j) {
                const unsigned short ha = bf16_rne(ea[j]);
                ahv[j] = (short)ha;
                alv[j] = (short)bf16_rne(ea[j] - bf16_to_f32(ha));
                const unsigned short hw = bf16_rne(ew[j]);
                whv[j] = (short)hw;
                wlv[j] = (short)bf16_rne(ew[j] - bf16_to_f32(hw));
            }
            const int slot = ((kc0 + s) * 128 + sr) * 8;
            *(bf16x8*)&Ah[slot] = ahv;
            *(bf16x8*)&Al[slot] = alv;
            *(bf16x8*)&Wh[slot] = whv;
            *(bf16x8*)&Wl[slot] = wlv;
        }

        // ---- prefetch next K-step into regs (hides under MFMA phase) ----
        if (k0 + 32 < K) {
            #pragma unroll
            for (int i = 0; i < 4; ++i) {
                ra[i] = *(const float4*)(Ap + k0 + 32 + i * 4);
                rw[i] = *(const float4*)(Wp + k0 + 32 + i * 4);
            }
        }

        __syncthreads();                  // LDS writes visible

        // ---- MFMA phase: 48 MFMA / wave / K-step ----
        bf16x8 whf[4], wlf[4];
        #pragma unroll
        for (int nj = 0; nj < 4; ++nj) {
            whf[nj] = *(const bf16x8*)&Wh[(fk * 128 + wn + nj * 16 + fr) * 8];
            wlf[nj] = *(const bf16x8*)&Wl[(fk * 128 + wn + nj * 16 + fr) * 8];
        }
        #pragma unroll
        for (int mi = 0; mi < 4; ++mi) {
            const bf16x8 ah = *(const bf16x8*)&Ah[(fk * 128 + wm + mi * 16 + fr) * 8];
            const bf16x8 al = *(const bf16x8*)&Al[(fk * 128 + wm + mi * 16 + fr) * 8];
            #pragma unroll
            for (int nj = 0; nj < 4; ++nj) {
                acc[mi][nj] = __builtin_amdgcn_mfma_f32_16x16x32_bf16(ah, whf[nj], acc[mi][nj], 0, 0, 0);
                acc[mi][nj] = __builtin_amdgcn_mfma_f32_16x16x32_bf16(ah, wlf[nj], acc[mi][nj], 0, 0, 0);
                acc[mi][nj] = __builtin_amdgcn_mfma_f32_16x16x32_bf16(al, whf[nj], acc[mi][nj], 0, 0, 0);
            }
        }
    }

    // ---- epilogue: bias add + fp32 store ----
    #pragma unroll
    for (int mi = 0; mi < 4; ++mi) {
        const int row0 = bm + wm + mi * 16 + fk * 4;
        #pragma unroll
        for (int nj = 0; nj < 4; ++nj) {
            const int col = bn + wn + nj * 16 + fr;
            const float bb = bias[col];
            float* cp = C + (size_t)row0 * N + col;
            #pragma unroll
            for (int j = 0; j < 4; ++j)
                cp[(size_t)j * N] = acc[mi][nj][j] + bb;
        }
    }
}

// ---------------------------------------------------------------------------
// Flash-style causal attention (unchanged from passing R2 version).
// ---------------------------------------------------------------------------
__global__ __launch_bounds__(256) void attn_causal(
    const float* __restrict__ Qg, const float* __restrict__ Kg,
    const float* __restrict__ Vg, float* __restrict__ Og)
{
    __shared__ __align__(16) float Qt[64][68];   // [d][qrow]
    __shared__ __align__(16) float KVs[64][68];  // K phase: [d][krow]; V phase: [krow][d]
    __shared__ __align__(16) float Pt[64][68];   // [kcol][qrow]

    const int tid = threadIdx.x;
    const int bh = blockIdx.x;
    const int b = bh >> 4, h = bh & 15;
    const int qt = blockIdx.y;

    const size_t base = (size_t)b * SEQ * EMBED + (size_t)h * HDIM;

    const int lr = tid >> 2;
    const int d0 = (tid & 3) << 4;

    {
        const float* qp = Qg + base + (size_t)(qt*64 + lr) * EMBED + d0;
        #pragma unroll
        for (int i = 0; i < 16; i += 4) {
            const float4 q4 = *(const float4*)(qp + i);
            Qt[d0+i+0][lr] = q4.x; Qt[d0+i+1][lr] = q4.y;
            Qt[d0+i+2][lr] = q4.z; Qt[d0+i+3][lr] = q4.w;
        }
    }

    const int tm = (tid >> 4) << 2;
    const int tn = (tid & 15) << 2;

    float m_i[4], l_i[4], o[4][4];
    #pragma unroll
    for (int i = 0; i < 4; ++i) {
        m_i[i] = -1e30f; l_i[i] = 0.f;
        #pragma unroll
        for (int j = 0; j < 4; ++j) o[i][j] = 0.f;
    }

    for (int kt = 0; kt <= qt; ++kt) {
        __syncthreads();
        {
            const float* kp = Kg + base + (size_t)(kt*64 + lr) * EMBED + d0;
            #pragma unroll
            for (int i = 0; i < 16; i += 4) {
                const float4 k4 = *(const float4*)(kp + i);
                KVs[d0+i+0][lr] = k4.x; KVs[d0+i+1][lr] = k4.y;
                KVs[d0+i+2][lr] = k4.z; KVs[d0+i+3][lr] = k4.w;
            }
        }
        __syncthreads();

        float sc[4][4] = {{0.f}};
        #pragma unroll 8
        for (int kk = 0; kk < 64; ++kk) {
            const float4 a = *(const float4*)&Qt[kk][tm];
            const float4 bb = *(const float4*)&KVs[kk][tn];
            const float a4[4] = {a.x,a.y,a.z,a.w};
            const float b4[4] = {bb.x,bb.y,bb.z,bb.w};
            #pragma unroll
            for (int i = 0; i < 4; ++i)
                #pragma unroll
                for (int j = 0; j < 4; ++j)
                    sc[i][j] = fmaf(a4[i], b4[j], sc[i][j]);
        }

        const bool diag = (kt == qt);
        #pragma unroll
        for (int i = 0; i < 4; ++i)
            #pragma unroll
            for (int j = 0; j < 4; ++j) {
                float s = sc[i][j] * 0.125f;
                if (diag && (tn + j > tm + i)) s = -1e30f;
                sc[i][j] = s;
            }

        #pragma unroll
        for (int i = 0; i < 4; ++i) {
            float mx = fmaxf(fmaxf(sc[i][0], sc[i][1]), fmaxf(sc[i][2], sc[i][3]));
            mx = fmaxf(mx, __shfl_xor(mx, 1));
            mx = fmaxf(mx, __shfl_xor(mx, 2));
            mx = fmaxf(mx, __shfl_xor(mx, 4));
            mx = fmaxf(mx, __shfl_xor(mx, 8));
            const float mnew = fmaxf(m_i[i], mx);
            const float corr = __expf(m_i[i] - mnew);
            float ps = 0.f;
            #pragma unroll
            for (int j = 0; j < 4; ++j) {
                const float p = __expf(sc[i][j] - mnew);
                Pt[tn+j][tm+i] = p;
                ps += p;
            }
            ps += __shfl_xor(ps, 1);
            ps += __shfl_xor(ps, 2);
            ps += __shfl_xor(ps, 4);
            ps += __shfl_xor(ps, 8);
            l_i[i] = l_i[i] * corr + ps;
            m_i[i] = mnew;
            #pragma unroll
            for (int j = 0; j < 4; ++j) o[i][j] *= corr;
        }

        __syncthreads();

        {
            const float* vp = Vg + base + (size_t)(kt*64 + lr) * EMBED + d0;
            #pragma unroll
            for (int i = 0; i < 16; i += 4)
                *(float4*)&KVs[lr][d0+i] = *(const float4*)(vp + i);
        }
        __syncthreads();

        #pragma unroll 8
        for (int c = 0; c < 64; ++c) {
            const float4 a = *(const float4*)&Pt[c][tm];
            const float4 bb = *(const float4*)&KVs[c][tn];
            const float a4[4] = {a.x,a.y,a.z,a.w};
            const float b4[4] = {bb.x,bb.y,bb.z,bb.w};
            #pragma unroll
            for (int i = 0; i < 4; ++i)
                #pragma unroll
                for (int j = 0; j < 4; ++j)
                    o[i][j] = fmaf(a4[i], b4[j], o[i][j]);
        }
    }

    #pragma unroll
    for (int i = 0; i < 4; ++i) {
        const float inv = 1.f / l_i[i];
        float4 r;
        r.x = o[i][0]*inv; r.y = o[i][1]*inv; r.z = o[i][2]*inv; r.w = o[i][3]*inv;
        *(float4*)(Og + base + (size_t)(qt*64 + tm + i) * EMBED + tn) = r;
    }
}

// ---------------------------------------------------------------------------
extern "C" void kernel_launch(void* const* d_in, const int* in_sizes, int n_in,
                              void* d_out, int out_size, void* d_ws, size_t ws_size,
                              hipStream_t stream)
{
    const float* x  = (const float*)d_in[0];
    const float* Wq = (const float*)d_in[1];
    const float* bq = (const float*)d_in[2];
    const float* Wk = (const float*)d_in[3];
    const float* bk = (const float*)d_in[4];
    const float* Wv = (const float*)d_in[5];
    const float* bv = (const float*)d_in[6];
    const float* Wo = (const float*)d_in[7];
    const float* bo = (const float*)d_in[8];
    float* out = (float*)d_out;

    const size_t BUF = (size_t)MROWS * EMBED;      // 4M floats = 16 MB
    if (ws_size < 2 * BUF * sizeof(float)) return; // proven-safe ws bound

    float* q = (float*)d_ws;                       // ws[0:16MB)
    float* k = q + BUF;                            // ws[16MB:32MB)
    float* v = out;                                // dead before final GEMM writes
    float* ctx = q;                                // disjoint per-block read->write

    dim3 gg(MROWS/128, EMBED/128);
    gemm_nt_bf16x3<<<gg, 256, 0, stream>>>(x, Wq, bq, q, MROWS, EMBED, EMBED);
    gemm_nt_bf16x3<<<gg, 256, 0, stream>>>(x, Wk, bk, k, MROWS, EMBED, EMBED);
    gemm_nt_bf16x3<<<gg, 256, 0, stream>>>(x, Wv, bv, v, MROWS, EMBED, EMBED);
    attn_causal<<<dim3(NHEADS*2, SEQ/64), 256, 0, stream>>>(q, k, v, ctx);
    gemm_nt_bf16x3<<<gg, 256, 0, stream>>>(ctx, Wo, bo, out, MROWS, EMBED, EMBED);
}

// Round 12
// 386.085 us; speedup vs baseline: 2.3834x; 1.5613x over previous
//
#include <hip/hip_runtime.h>
#include <hip/hip_bf16.h>

// Fused causal MHA forward. B=2, S=2048, E=1024, H=16, D=64.
// R5-R12: attention on MFMA (pure bf16 QK^T and PV, fp32 online softmax).
// Projection GEMMs unchanged (bf16x3 MFMA, passing at absmax 3.9e-3).

#define SEQ   2048
#define EMBED 1024
#define NHEADS 16
#define HDIM  64
#define MROWS 4096  // B*S

typedef __attribute__((ext_vector_type(8))) short bf16x8;
typedef __attribute__((ext_vector_type(4))) float f32x4;

__device__ __forceinline__ unsigned short bf16_rne(float x) {
    unsigned u = __builtin_bit_cast(unsigned, x);
    unsigned r = u + 0x7fffu + ((u >> 16) & 1u);   // round-to-nearest-even
    return (unsigned short)(r >> 16);
}
__device__ __forceinline__ float bf16_to_f32(unsigned short h) {
    return __builtin_bit_cast(float, (unsigned)h << 16);
}
__device__ __forceinline__ unsigned short bf16s(float x) {
    return __builtin_bit_cast(unsigned short, __float2bfloat16(x));
}

// ---------------------------------------------------------------------------
// C[M,N] = A[M,K] @ W[N,K]^T + bias[N], fp32 in/out, bf16x3 MFMA compute.
// (unchanged from passing R4 version)
// ---------------------------------------------------------------------------
__global__ __launch_bounds__(256) void gemm_nt_bf16x3(
    const float* __restrict__ A, const float* __restrict__ W,
    const float* __restrict__ bias, float* __restrict__ C,
    int M, int N, int K)
{
    __shared__ __align__(16) unsigned short Ah[4096];
    __shared__ __align__(16) unsigned short Al[4096];
    __shared__ __align__(16) unsigned short Wh[4096];
    __shared__ __align__(16) unsigned short Wl[4096];

    const int tid = threadIdx.x;
    const int bm = blockIdx.x * 128;
    const int bn = blockIdx.y * 128;

    const int sr  = tid >> 1;
    const int sk  = (tid & 1) * 16;
    const int kc0 = (tid & 1) * 2;

    const float* Ap = A + (size_t)(bm + sr) * K + sk;
    const float* Wp = W + (size_t)(bn + sr) * K + sk;

    const int lane = tid & 63;
    const int wv = tid >> 6;
    const int wm = (wv >> 1) * 64;
    const int wn = (wv & 1) * 64;
    const int fr = lane & 15;
    const int fk = lane >> 4;

    f32x4 acc[4][4];
    #pragma unroll
    for (int i = 0; i < 4; ++i)
        #pragma unroll
        for (int j = 0; j < 4; ++j)
            acc[i][j] = (f32x4){0.f, 0.f, 0.f, 0.f};

    float4 ra[4], rw[4];
    #pragma unroll
    for (int i = 0; i < 4; ++i) {
        ra[i] = *(const float4*)(Ap + i * 4);
        rw[i] = *(const float4*)(Wp + i * 4);
    }

    for (int k0 = 0; k0 < K; k0 += 32) {
        __syncthreads();

        #pragma unroll
        for (int s = 0; s < 2; ++s) {
            const float ea[8] = { ra[2*s].x, ra[2*s].y, ra[2*s].z, ra[2*s].w,
                                  ra[2*s+1].x, ra[2*s+1].y, ra[2*s+1].z, ra[2*s+1].w };
            const float ew[8] = { rw[2*s].x, rw[2*s].y, rw[2*s].z, rw[2*s].w,
                                  rw[2*s+1].x, rw[2*s+1].y, rw[2*s+1].z, rw[2*s+1].w };
            bf16x8 ahv, alv, whv, wlv;
            #pragma unroll
            for (int j = 0; j < 8; ++j) {
                const unsigned short ha = bf16_rne(ea[j]);
                ahv[j] = (short)ha;
                alv[j] = (short)bf16_rne(ea[j] - bf16_to_f32(ha));
                const unsigned short hw = bf16_rne(ew[j]);
                whv[j] = (short)hw;
                wlv[j] = (short)bf16_rne(ew[j] - bf16_to_f32(hw));
            }
            const int slot = ((kc0 + s) * 128 + sr) * 8;
            *(bf16x8*)&Ah[slot] = ahv;
            *(bf16x8*)&Al[slot] = alv;
            *(bf16x8*)&Wh[slot] = whv;
            *(bf16x8*)&Wl[slot] = wlv;
        }

        if (k0 + 32 < K) {
            #pragma unroll
            for (int i = 0; i < 4; ++i) {
                ra[i] = *(const float4*)(Ap + k0 + 32 + i * 4);
                rw[i] = *(const float4*)(Wp + k0 + 32 + i * 4);
            }
        }

        __syncthreads();

        bf16x8 whf[4], wlf[4];
        #pragma unroll
        for (int nj = 0; nj < 4; ++nj) {
            whf[nj] = *(const bf16x8*)&Wh[(fk * 128 + wn + nj * 16 + fr) * 8];
            wlf[nj] = *(const bf16x8*)&Wl[(fk * 128 + wn + nj * 16 + fr) * 8];
        }
        #pragma unroll
        for (int mi = 0; mi < 4; ++mi) {
            const bf16x8 ah = *(const bf16x8*)&Ah[(fk * 128 + wm + mi * 16 + fr) * 8];
            const bf16x8 al = *(const bf16x8*)&Al[(fk * 128 + wm + mi * 16 + fr) * 8];
            #pragma unroll
            for (int nj = 0; nj < 4; ++nj) {
                acc[mi][nj] = __builtin_amdgcn_mfma_f32_16x16x32_bf16(ah, whf[nj], acc[mi][nj], 0, 0, 0);
                acc[mi][nj] = __builtin_amdgcn_mfma_f32_16x16x32_bf16(ah, wlf[nj], acc[mi][nj], 0, 0, 0);
                acc[mi][nj] = __builtin_amdgcn_mfma_f32_16x16x32_bf16(al, whf[nj], acc[mi][nj], 0, 0, 0);
            }
        }
    }

    #pragma unroll
    for (int mi = 0; mi < 4; ++mi) {
        const int row0 = bm + wm + mi * 16 + fk * 4;
        #pragma unroll
        for (int nj = 0; nj < 4; ++nj) {
            const int col = bn + wn + nj * 16 + fr;
            const float bb = bias[col];
            float* cp = C + (size_t)row0 * N + col;
            #pragma unroll
            for (int j = 0; j < 4; ++j)
                cp[(size_t)j * N] = acc[mi][nj][j] + bb;
        }
    }
}

// ---------------------------------------------------------------------------
// Flash attention on MFMA. One block per (b*H+h, q-tile of 64). 4 waves x
// 16 q-rows. Pure bf16 QK^T / PV, fp32 online softmax.
// mfma_f32_16x16x32_bf16: A lane holds A[l&15][(l>>4)*8+j] (per 32-k chunk);
// B lane holds B[(l>>4)*8+j][l&15]; D: col=lane&15, row=(lane>>4)*4+reg.
// K staged [krow][d] bf16 (rowpad 72); V staged transposed [d][c] (rowpad 72);
// P routed through per-wave LDS (same-wave DS ordering -> no barrier).
// ---------------------------------------------------------------------------
__global__ __launch_bounds__(256) void attn_mfma(
    const float* __restrict__ Qg, const float* __restrict__ Kg,
    const float* __restrict__ Vg, float* __restrict__ Og)
{
    __shared__ __align__(16) unsigned short Ks[64 * 72];
    __shared__ __align__(16) unsigned short Vt[64 * 72];
    __shared__ __align__(16) unsigned short Ps[4][16 * 72];

    const int tid = threadIdx.x;
    const int bh = blockIdx.x;
    const int b = bh >> 4, h = bh & 15;
    const int qt = blockIdx.y;
    const size_t base = (size_t)b * SEQ * EMBED + (size_t)h * HDIM;

    const int lane = tid & 63;
    const int wv = tid >> 6;          // wave 0..3, owns q-rows wv*16..+15
    const int fr = lane & 15;
    const int fq = lane >> 4;         // 0..3

    const int srow = tid >> 2;        // staging row 0..63
    const int sd0  = (tid & 3) * 16;  // staging d-chunk

    // ---- stage Q tile through Ks, pull A-fragments to registers ----
    {
        const float* qp = Qg + base + (size_t)(qt * 64 + srow) * EMBED + sd0;
        unsigned short tmp[16];
        #pragma unroll
        for (int i = 0; i < 16; i += 4) {
            const float4 q4 = *(const float4*)(qp + i);
            tmp[i+0] = bf16s(q4.x); tmp[i+1] = bf16s(q4.y);
            tmp[i+2] = bf16s(q4.z); tmp[i+3] = bf16s(q4.w);
        }
        *(bf16x8*)&Ks[srow * 72 + sd0]     = *(const bf16x8*)&tmp[0];
        *(bf16x8*)&Ks[srow * 72 + sd0 + 8] = *(const bf16x8*)&tmp[8];
    }
    __syncthreads();
    bf16x8 qf[2];
    qf[0] = *(const bf16x8*)&Ks[(wv * 16 + fr) * 72 +  0 + fq * 8];
    qf[1] = *(const bf16x8*)&Ks[(wv * 16 + fr) * 72 + 32 + fq * 8];

    float m_i[4], l_i[4];
    f32x4 o[4];
    #pragma unroll
    for (int r = 0; r < 4; ++r) { m_i[r] = -1e30f; l_i[r] = 0.f; }
    #pragma unroll
    for (int n = 0; n < 4; ++n) o[n] = (f32x4){0.f, 0.f, 0.f, 0.f};

    for (int kt = 0; kt <= qt; ++kt) {
        __syncthreads();              // all waves done reading Ks/Vt (& Q pull)

        {   // K tile -> Ks[row][d] bf16
            const float* kp = Kg + base + (size_t)(kt * 64 + srow) * EMBED + sd0;
            unsigned short tmp[16];
            #pragma unroll
            for (int i = 0; i < 16; i += 4) {
                const float4 k4 = *(const float4*)(kp + i);
                tmp[i+0] = bf16s(k4.x); tmp[i+1] = bf16s(k4.y);
                tmp[i+2] = bf16s(k4.z); tmp[i+3] = bf16s(k4.w);
            }
            *(bf16x8*)&Ks[srow * 72 + sd0]     = *(const bf16x8*)&tmp[0];
            *(bf16x8*)&Ks[srow * 72 + sd0 + 8] = *(const bf16x8*)&tmp[8];
        }
        {   // V tile -> Vt[d][c] bf16 (transposed scatter)
            const float* vp = Vg + base + (size_t)(kt * 64 + srow) * EMBED + sd0;
            #pragma unroll
            for (int i = 0; i < 16; i += 4) {
                const float4 v4 = *(const float4*)(vp + i);
                Vt[(sd0+i+0) * 72 + srow] = bf16s(v4.x);
                Vt[(sd0+i+1) * 72 + srow] = bf16s(v4.y);
                Vt[(sd0+i+2) * 72 + srow] = bf16s(v4.z);
                Vt[(sd0+i+3) * 72 + srow] = bf16s(v4.w);
            }
        }
        __syncthreads();

        // ---- S = Q K^T (8 MFMA) ----
        f32x4 sc[4];
        #pragma unroll
        for (int n = 0; n < 4; ++n) sc[n] = (f32x4){0.f, 0.f, 0.f, 0.f};
        #pragma unroll
        for (int kc = 0; kc < 2; ++kc)
            #pragma unroll
            for (int n = 0; n < 4; ++n) {
                const bf16x8 kf = *(const bf16x8*)&Ks[(n * 16 + fr) * 72 + kc * 32 + fq * 8];
                sc[n] = __builtin_amdgcn_mfma_f32_16x16x32_bf16(qf[kc], kf, sc[n], 0, 0, 0);
            }

        // ---- scale + causal mask ----
        const bool diag = (kt == qt);
        float t[4][4];
        #pragma unroll
        for (int n = 0; n < 4; ++n)
            #pragma unroll
            for (int r = 0; r < 4; ++r) {
                float s = sc[n][r] * 0.125f;
                if (diag && (n * 16 + fr > wv * 16 + fq * 4 + r)) s = -1e30f;
                t[n][r] = s;
            }

        // ---- online softmax (row = wv*16 + fq*4 + r; 16 lanes share a row) ----
        #pragma unroll
        for (int r = 0; r < 4; ++r) {
            float mx = fmaxf(fmaxf(t[0][r], t[1][r]), fmaxf(t[2][r], t[3][r]));
            mx = fmaxf(mx, __shfl_xor(mx, 1));
            mx = fmaxf(mx, __shfl_xor(mx, 2));
            mx = fmaxf(mx, __shfl_xor(mx, 4));
            mx = fmaxf(mx, __shfl_xor(mx, 8));
            const float mnew = fmaxf(m_i[r], mx);
            const float corr = __expf(m_i[r] - mnew);
            float ps = 0.f;
            #pragma unroll
            for (int n = 0; n < 4; ++n) {
                const float p = __expf(t[n][r] - mnew);
                Ps[wv][(fq * 4 + r) * 72 + n * 16 + fr] = bf16s(p);
                ps += p;
            }
            ps += __shfl_xor(ps, 1);
            ps += __shfl_xor(ps, 2);
            ps += __shfl_xor(ps, 4);
            ps += __shfl_xor(ps, 8);
            l_i[r] = l_i[r] * corr + ps;
            m_i[r] = mnew;
            o[0][r] *= corr; o[1][r] *= corr; o[2][r] *= corr; o[3][r] *= corr;
        }

        // ---- O += P V (8 MFMA); Ps is per-wave -> same-wave DS order, no barrier
        #pragma unroll
        for (int kc = 0; kc < 2; ++kc) {
            const bf16x8 pf = *(const bf16x8*)&Ps[wv][fr * 72 + kc * 32 + fq * 8];
            #pragma unroll
            for (int n = 0; n < 4; ++n) {
                const bf16x8 vf = *(const bf16x8*)&Vt[(n * 16 + fr) * 72 + kc * 32 + fq * 8];
                o[n] = __builtin_amdgcn_mfma_f32_16x16x32_bf16(pf, vf, o[n], 0, 0, 0);
            }
        }
    }

    // ---- epilogue: normalize, write ctx ----
    #pragma unroll
    for (int r = 0; r < 4; ++r) {
        const float inv = 1.f / l_i[r];
        float* op = Og + base + (size_t)(qt * 64 + wv * 16 + fq * 4 + r) * EMBED;
        #pragma unroll
        for (int n = 0; n < 4; ++n)
            op[n * 16 + fr] = o[n][r] * inv;
    }
}

// ---------------------------------------------------------------------------
extern "C" void kernel_launch(void* const* d_in, const int* in_sizes, int n_in,
                              void* d_out, int out_size, void* d_ws, size_t ws_size,
                              hipStream_t stream)
{
    const float* x  = (const float*)d_in[0];
    const float* Wq = (const float*)d_in[1];
    const float* bq = (const float*)d_in[2];
    const float* Wk = (const float*)d_in[3];
    const float* bk = (const float*)d_in[4];
    const float* Wv = (const float*)d_in[5];
    const float* bv = (const float*)d_in[6];
    const float* Wo = (const float*)d_in[7];
    const float* bo = (const float*)d_in[8];
    float* out = (float*)d_out;

    const size_t BUF = (size_t)MROWS * EMBED;      // 4M floats = 16 MB
    if (ws_size < 2 * BUF * sizeof(float)) return; // proven-safe ws bound

    float* q = (float*)d_ws;                       // ws[0:16MB)
    float* k = q + BUF;                            // ws[16MB:32MB)
    float* v = out;                                // dead before final GEMM writes
    float* ctx = q;                                // disjoint per-block read->write

    dim3 gg(MROWS/128, EMBED/128);
    gemm_nt_bf16x3<<<gg, 256, 0, stream>>>(x, Wq, bq, q, MROWS, EMBED, EMBED);
    gemm_nt_bf16x3<<<gg, 256, 0, stream>>>(x, Wk, bk, k, MROWS, EMBED, EMBED);
    gemm_nt_bf16x3<<<gg, 256, 0, stream>>>(x, Wv, bv, v, MROWS, EMBED, EMBED);
    attn_mfma<<<dim3(NHEADS*2, SEQ/64), 256, 0, stream>>>(q, k, v, ctx);
    gemm_nt_bf16x3<<<gg, 256, 0, stream>>>(ctx, Wo, bo, out, MROWS, EMBED, EMBED);
}

// Round 13
// 313.084 us; speedup vs baseline: 2.9391x; 1.2332x over previous
//
#include <hip/hip_runtime.h>
#include <hip/hip_bf16.h>

// Fused causal MHA forward. B=2, S=2048, E=1024, H=16, D=64.
// R13: bf16-interface refactor. Pre-pass kernels split x/W into bf16 hi/lo;
// GEMMs stage pure bf16 copies (no in-loop conversion); q/k/v produced in
// bf16; V pre-transposed by the V-GEMM epilogue (kills the 8-way-conflict
// LDS scatter in attn); Q fragments read per-lane from global. ctx kept at
// fp32 accuracy as bf16 hi/lo pair. Core MFMA/softmax logic byte-identical
// to the R12 kernel that passed at absmax 7.8e-3.

#define SEQ   2048
#define EMBED 1024
#define NHEADS 16
#define HDIM  64
#define MROWS 4096  // B*S

typedef __attribute__((ext_vector_type(8))) short bf16x8;
typedef __attribute__((ext_vector_type(4))) float f32x4;
typedef unsigned short ush;

__device__ __forceinline__ ush bf16_rne(float x) {
    unsigned u = __builtin_bit_cast(unsigned, x);
    unsigned r = u + 0x7fffu + ((u >> 16) & 1u);   // round-to-nearest-even
    return (ush)(r >> 16);
}
__device__ __forceinline__ float bf16_to_f32(ush h) {
    return __builtin_bit_cast(float, (unsigned)h << 16);
}

// ---------------------------------------------------------------------------
// fp32 -> bf16 hi/lo split, elementwise (grid-stride over float4 groups).
// ---------------------------------------------------------------------------
__global__ __launch_bounds__(256) void conv_hilo(
    const float* __restrict__ src, ush* __restrict__ hi, ush* __restrict__ lo,
    int n4)
{
    int i = blockIdx.x * blockDim.x + threadIdx.x;
    const int stride = gridDim.x * blockDim.x;
    for (; i < n4; i += stride) {
        const float4 v = ((const float4*)src)[i];
        ushort4 h, l;
        h.x = bf16_rne(v.x); l.x = bf16_rne(v.x - bf16_to_f32(h.x));
        h.y = bf16_rne(v.y); l.y = bf16_rne(v.y - bf16_to_f32(h.y));
        h.z = bf16_rne(v.z); l.z = bf16_rne(v.z - bf16_to_f32(h.z));
        h.w = bf16_rne(v.w); l.w = bf16_rne(v.w - bf16_to_f32(h.w));
        ((ushort4*)hi)[i] = h;
        ((ushort4*)lo)[i] = l;
    }
}

// ---------------------------------------------------------------------------
// C = A @ W^T + bias. All inputs pre-converted bf16 hi/lo. bf16x3 MFMA.
// 128x128 tile, BK=32, 256 threads, 4 waves 2x2, 64x64/wave.
// Staging is a pure copy: 2x16B global load + 2x ds_write_b128 per buffer.
// OMODE: 0 = bf16 row-major [M][N], 1 = bf16 transposed per-batch [N][2048]
// (for v_t), 2 = fp32 row-major.
// ---------------------------------------------------------------------------
template<int OMODE>
__global__ __launch_bounds__(256) void gemm_pre(
    const ush* __restrict__ Ah_g, const ush* __restrict__ Al_g,
    const ush* __restrict__ Wh_g, const ush* __restrict__ Wl_g,
    const float* __restrict__ bias, void* __restrict__ Cv,
    int M, int N, int K)
{
    __shared__ __align__(16) ush Ah[4096];
    __shared__ __align__(16) ush Al[4096];
    __shared__ __align__(16) ush Wh[4096];
    __shared__ __align__(16) ush Wl[4096];

    const int tid = threadIdx.x;
    const int bm = blockIdx.x * 128;
    const int bn = blockIdx.y * 128;

    const int sr  = tid >> 1;            // 0..127 staged row
    const int kc0 = (tid & 1) * 2;       // first kchunk (of 4 per K-step)

    const ush* Ap  = Ah_g + (size_t)(bm + sr) * K + kc0 * 8;
    const ush* Alp = Al_g + (size_t)(bm + sr) * K + kc0 * 8;
    const ush* Wp  = Wh_g + (size_t)(bn + sr) * K + kc0 * 8;
    const ush* Wlp = Wl_g + (size_t)(bn + sr) * K + kc0 * 8;

    const int lane = tid & 63;
    const int wv = tid >> 6;
    const int wm = (wv >> 1) * 64;
    const int wn = (wv & 1) * 64;
    const int fr = lane & 15;
    const int fk = lane >> 4;

    f32x4 acc[4][4];
    #pragma unroll
    for (int i = 0; i < 4; ++i)
        #pragma unroll
        for (int j = 0; j < 4; ++j)
            acc[i][j] = (f32x4){0.f, 0.f, 0.f, 0.f};

    bf16x8 rah[2], ral[2], rwh[2], rwl[2];
    #pragma unroll
    for (int s = 0; s < 2; ++s) {        // prologue: K-step 0
        rah[s] = *(const bf16x8*)(Ap  + s * 8);
        ral[s] = *(const bf16x8*)(Alp + s * 8);
        rwh[s] = *(const bf16x8*)(Wp  + s * 8);
        rwl[s] = *(const bf16x8*)(Wlp + s * 8);
    }

    for (int k0 = 0; k0 < K; k0 += 32) {
        __syncthreads();                 // prior MFMA reads done

        #pragma unroll
        for (int s = 0; s < 2; ++s) {
            const int slot = ((kc0 + s) * 128 + sr) * 8;
            *(bf16x8*)&Ah[slot] = rah[s];
            *(bf16x8*)&Al[slot] = ral[s];
            *(bf16x8*)&Wh[slot] = rwh[s];
            *(bf16x8*)&Wl[slot] = rwl[s];
        }

        if (k0 + 32 < K) {               // prefetch next K-step
            #pragma unroll
            for (int s = 0; s < 2; ++s) {
                rah[s] = *(const bf16x8*)(Ap  + k0 + 32 + s * 8);
                ral[s] = *(const bf16x8*)(Alp + k0 + 32 + s * 8);
                rwh[s] = *(const bf16x8*)(Wp  + k0 + 32 + s * 8);
                rwl[s] = *(const bf16x8*)(Wlp + k0 + 32 + s * 8);
            }
        }

        __syncthreads();                 // LDS visible

        bf16x8 whf[4], wlf[4];
        #pragma unroll
        for (int nj = 0; nj < 4; ++nj) {
            whf[nj] = *(const bf16x8*)&Wh[(fk * 128 + wn + nj * 16 + fr) * 8];
            wlf[nj] = *(const bf16x8*)&Wl[(fk * 128 + wn + nj * 16 + fr) * 8];
        }
        #pragma unroll
        for (int mi = 0; mi < 4; ++mi) {
            const bf16x8 ah = *(const bf16x8*)&Ah[(fk * 128 + wm + mi * 16 + fr) * 8];
            const bf16x8 al = *(const bf16x8*)&Al[(fk * 128 + wm + mi * 16 + fr) * 8];
            #pragma unroll
            for (int nj = 0; nj < 4; ++nj) {
                acc[mi][nj] = __builtin_amdgcn_mfma_f32_16x16x32_bf16(ah, whf[nj], acc[mi][nj], 0, 0, 0);
                acc[mi][nj] = __builtin_amdgcn_mfma_f32_16x16x32_bf16(ah, wlf[nj], acc[mi][nj], 0, 0, 0);
                acc[mi][nj] = __builtin_amdgcn_mfma_f32_16x16x32_bf16(al, whf[nj], acc[mi][nj], 0, 0, 0);
            }
        }
    }

    // ---- epilogue ----
    #pragma unroll
    for (int mi = 0; mi < 4; ++mi) {
        const int row0 = bm + wm + mi * 16 + fk * 4;
        #pragma unroll
        for (int nj = 0; nj < 4; ++nj) {
            const int col = bn + wn + nj * 16 + fr;
            const float bb = bias[col];
            if (OMODE == 2) {
                float* cp = (float*)Cv + (size_t)row0 * N + col;
                #pragma unroll
                for (int j = 0; j < 4; ++j)
                    cp[(size_t)j * N] = acc[mi][nj][j] + bb;
            } else if (OMODE == 0) {
                ush* cp = (ush*)Cv + (size_t)row0 * N + col;
                #pragma unroll
                for (int j = 0; j < 4; ++j)
                    cp[(size_t)j * N] = bf16_rne(acc[mi][nj][j] + bb);
            } else {                     // OMODE 1: v_t[b][col][s], s=row%2048
                const int bb_ = row0 >> 11, s0 = row0 & 2047;
                ushort4 pk;
                pk.x = bf16_rne(acc[mi][nj][0] + bb);
                pk.y = bf16_rne(acc[mi][nj][1] + bb);
                pk.z = bf16_rne(acc[mi][nj][2] + bb);
                pk.w = bf16_rne(acc[mi][nj][3] + bb);
                *(ushort4*)((ush*)Cv + (size_t)bb_ * EMBED * SEQ
                            + (size_t)col * SEQ + s0) = pk;
            }
        }
    }
}

// ---------------------------------------------------------------------------
// Flash attention on MFMA, bf16 inputs. Q frags per-lane from global;
// K staged [krow][d]; V^T staged [d][c] via straight b128 row copies from
// the pre-transposed v_t (no scatter). fp32 online softmax unchanged.
// Output ctx as bf16 hi/lo pair (fp32 accuracy for the final GEMM).
// ---------------------------------------------------------------------------
__global__ __launch_bounds__(256) void attn_mfma2(
    const ush* __restrict__ Qg, const ush* __restrict__ Kg,
    const ush* __restrict__ Vtg, ush* __restrict__ Oh, ush* __restrict__ Ol)
{
    __shared__ __align__(16) ush Ks[64 * 72];
    __shared__ __align__(16) ush Vs[64 * 72];
    __shared__ __align__(16) ush Ps[4][16 * 72];

    const int tid = threadIdx.x;
    const int bh = blockIdx.x;
    const int b = bh >> 4, h = bh & 15;
    const int qt = blockIdx.y;

    const int lane = tid & 63;
    const int wv = tid >> 6;          // wave owns q-rows wv*16..+15
    const int fr = lane & 15;
    const int fq = lane >> 4;         // 0..3

    const int sr2 = tid >> 2;         // staging row 0..63
    const int sc  = (tid & 3) * 16;   // staging 16-short chunk

    // ---- Q fragments straight from global (row qt*64+wv*16+fr) ----
    const ush* qp = Qg + ((size_t)(b * SEQ + qt * 64 + wv * 16 + fr)) * EMBED
                       + h * HDIM;
    bf16x8 qf[2];
    qf[0] = *(const bf16x8*)(qp +  0 + fq * 8);
    qf[1] = *(const bf16x8*)(qp + 32 + fq * 8);

    float m_i[4], l_i[4];
    f32x4 o[4];
    #pragma unroll
    for (int r = 0; r < 4; ++r) { m_i[r] = -1e30f; l_i[r] = 0.f; }
    #pragma unroll
    for (int n = 0; n < 4; ++n) o[n] = (f32x4){0.f, 0.f, 0.f, 0.f};

    for (int kt = 0; kt <= qt; ++kt) {
        __syncthreads();              // all waves done reading Ks/Vs

        {   // K tile: row sr2, 32B copy
            const ush* kp = Kg + ((size_t)(b * SEQ + kt * 64 + sr2)) * EMBED
                               + h * HDIM + sc;
            *(bf16x8*)&Ks[sr2 * 72 + sc]     = *(const bf16x8*)kp;
            *(bf16x8*)&Ks[sr2 * 72 + sc + 8] = *(const bf16x8*)(kp + 8);
        }
        {   // V^T tile: d-row sr2, 32B copy from pre-transposed v_t
            const ush* vp = Vtg + ((size_t)b * EMBED + h * HDIM + sr2) * SEQ
                                + kt * 64 + sc;
            *(bf16x8*)&Vs[sr2 * 72 + sc]     = *(const bf16x8*)vp;
            *(bf16x8*)&Vs[sr2 * 72 + sc + 8] = *(const bf16x8*)(vp + 8);
        }
        __syncthreads();

        // ---- S = Q K^T (8 MFMA) ----
        f32x4 sc4[4];
        #pragma unroll
        for (int n = 0; n < 4; ++n) sc4[n] = (f32x4){0.f, 0.f, 0.f, 0.f};
        #pragma unroll
        for (int kc = 0; kc < 2; ++kc)
            #pragma unroll
            for (int n = 0; n < 4; ++n) {
                const bf16x8 kf = *(const bf16x8*)&Ks[(n * 16 + fr) * 72 + kc * 32 + fq * 8];
                sc4[n] = __builtin_amdgcn_mfma_f32_16x16x32_bf16(qf[kc], kf, sc4[n], 0, 0, 0);
            }

        // ---- scale + causal mask ----
        const bool diag = (kt == qt);
        float t[4][4];
        #pragma unroll
        for (int n = 0; n < 4; ++n)
            #pragma unroll
            for (int r = 0; r < 4; ++r) {
                float s = sc4[n][r] * 0.125f;
                if (diag && (n * 16 + fr > wv * 16 + fq * 4 + r)) s = -1e30f;
                t[n][r] = s;
            }

        // ---- online softmax (16 lanes share q-row wv*16+fq*4+r) ----
        #pragma unroll
        for (int r = 0; r < 4; ++r) {
            float mx = fmaxf(fmaxf(t[0][r], t[1][r]), fmaxf(t[2][r], t[3][r]));
            mx = fmaxf(mx, __shfl_xor(mx, 1));
            mx = fmaxf(mx, __shfl_xor(mx, 2));
            mx = fmaxf(mx, __shfl_xor(mx, 4));
            mx = fmaxf(mx, __shfl_xor(mx, 8));
            const float mnew = fmaxf(m_i[r], mx);
            const float corr = __expf(m_i[r] - mnew);
            float ps = 0.f;
            #pragma unroll
            for (int n = 0; n < 4; ++n) {
                const float p = __expf(t[n][r] - mnew);
                Ps[wv][(fq * 4 + r) * 72 + n * 16 + fr] = bf16_rne(p);
                ps += p;
            }
            ps += __shfl_xor(ps, 1);
            ps += __shfl_xor(ps, 2);
            ps += __shfl_xor(ps, 4);
            ps += __shfl_xor(ps, 8);
            l_i[r] = l_i[r] * corr + ps;
            m_i[r] = mnew;
            o[0][r] *= corr; o[1][r] *= corr; o[2][r] *= corr; o[3][r] *= corr;
        }

        // ---- O += P V (8 MFMA); Ps per-wave, same-wave DS order ----
        #pragma unroll
        for (int kc = 0; kc < 2; ++kc) {
            const bf16x8 pf = *(const bf16x8*)&Ps[wv][fr * 72 + kc * 32 + fq * 8];
            #pragma unroll
            for (int n = 0; n < 4; ++n) {
                const bf16x8 vf = *(const bf16x8*)&Vs[(n * 16 + fr) * 72 + kc * 32 + fq * 8];
                o[n] = __builtin_amdgcn_mfma_f32_16x16x32_bf16(pf, vf, o[n], 0, 0, 0);
            }
        }
    }

    // ---- epilogue: normalize, write ctx hi/lo ----
    #pragma unroll
    for (int r = 0; r < 4; ++r) {
        const float inv = 1.f / l_i[r];
        const size_t rowoff = ((size_t)(b * SEQ + qt * 64 + wv * 16 + fq * 4 + r)) * EMBED
                              + h * HDIM;
        #pragma unroll
        for (int n = 0; n < 4; ++n) {
            const float val = o[n][r] * inv;
            const ush hv = bf16_rne(val);
            Oh[rowoff + n * 16 + fr] = hv;
            Ol[rowoff + n * 16 + fr] = bf16_rne(val - bf16_to_f32(hv));
        }
    }
}

// ---------------------------------------------------------------------------
extern "C" void kernel_launch(void* const* d_in, const int* in_sizes, int n_in,
                              void* d_out, int out_size, void* d_ws, size_t ws_size,
                              hipStream_t stream)
{
    const float* x  = (const float*)d_in[0];
    const float* Wq = (const float*)d_in[1];
    const float* bq = (const float*)d_in[2];
    const float* Wk = (const float*)d_in[3];
    const float* bk = (const float*)d_in[4];
    const float* Wv = (const float*)d_in[5];
    const float* bv = (const float*)d_in[6];
    const float* Wo = (const float*)d_in[7];
    const float* bo = (const float*)d_in[8];
    float* out = (float*)d_out;

    const size_t XN = (size_t)MROWS * EMBED;       // 4M elems
    const size_t WN = (size_t)EMBED * EMBED;       // 1M elems
    if (ws_size < 2 * XN * sizeof(float)) return;  // proven-safe 32 MB bound

    // ws (ushort view, 16M shorts):
    //   [0:4M)  q_bf16  -> ctx_hi (per-block disjoint read->write)
    //   [4M:8M) k_bf16
    //   [8M:12M) x_hi   -> ctx_lo  (x dead after V GEMM)
    //   [12M:16M) x_lo  -> Wo_h [12M:13M) + Wo_l [13M:14M)
    ush* wsu  = (ush*)d_ws;
    ush* qb   = wsu;
    ush* kb   = wsu + XN;
    ush* x_hi = wsu + 2 * XN;
    ush* x_lo = wsu + 3 * XN;
    ush* ctx_hi = qb;
    ush* ctx_lo = x_hi;
    ush* wo_h = x_lo;
    ush* wo_l = x_lo + WN;

    // d_out (ushort view, 8M shorts):
    //   [0:4M) v_t bf16 (per-batch [EMBED][SEQ]); [4M:5M) W_hi; [5M:6M) W_lo
    //   final fp32 out overwrites everything (all scratch dead by then)
    ush* dov  = (ush*)d_out;
    ush* vt   = dov;
    ush* w_hi = dov + XN;
    ush* w_lo = dov + XN + WN;

    dim3 gg(MROWS / 128, EMBED / 128);

    conv_hilo<<<2048, 256, 0, stream>>>(x, x_hi, x_lo, (int)(XN / 4));

    conv_hilo<<<1024, 256, 0, stream>>>(Wq, w_hi, w_lo, (int)(WN / 4));
    gemm_pre<0><<<gg, 256, 0, stream>>>(x_hi, x_lo, w_hi, w_lo, bq, qb, MROWS, EMBED, EMBED);

    conv_hilo<<<1024, 256, 0, stream>>>(Wk, w_hi, w_lo, (int)(WN / 4));
    gemm_pre<0><<<gg, 256, 0, stream>>>(x_hi, x_lo, w_hi, w_lo, bk, kb, MROWS, EMBED, EMBED);

    conv_hilo<<<1024, 256, 0, stream>>>(Wv, w_hi, w_lo, (int)(WN / 4));
    gemm_pre<1><<<gg, 256, 0, stream>>>(x_hi, x_lo, w_hi, w_lo, bv, vt, MROWS, EMBED, EMBED);

    attn_mfma2<<<dim3(NHEADS * 2, SEQ / 64), 256, 0, stream>>>(qb, kb, vt, ctx_hi, ctx_lo);

    conv_hilo<<<1024, 256, 0, stream>>>(Wo, wo_h, wo_l, (int)(WN / 4));
    gemm_pre<2><<<gg, 256, 0, stream>>>(ctx_hi, ctx_lo, wo_h, wo_l, bo, out, MROWS, EMBED, EMBED);
}

// Round 14
// 276.590 us; speedup vs baseline: 3.3269x; 1.1319x over previous
//
#include <hip/hip_runtime.h>
#include <hip/hip_bf16.h>

// Fused causal MHA forward. B=2, S=2048, E=1024, H=16, D=64.
// R14: attn de-serialization — double-buffered K/V staging (loads issued
// before compute, written after), per-lane partial softmax sums (reduce once
// in epilogue), defer-max (THR=8, skip cross-lane max+rescale when no lane
// exceeds m+8), reversed qt dispatch (longest blocks first).
// GEMM/conv pipeline unchanged from R13 (passed at 313 us, absmax 7.8e-3).

#define SEQ   2048
#define EMBED 1024
#define NHEADS 16
#define HDIM  64
#define MROWS 4096  // B*S

typedef __attribute__((ext_vector_type(8))) short bf16x8;
typedef __attribute__((ext_vector_type(4))) float f32x4;
typedef unsigned short ush;

__device__ __forceinline__ ush bf16_rne(float x) {
    unsigned u = __builtin_bit_cast(unsigned, x);
    unsigned r = u + 0x7fffu + ((u >> 16) & 1u);   // round-to-nearest-even
    return (ush)(r >> 16);
}
__device__ __forceinline__ float bf16_to_f32(ush h) {
    return __builtin_bit_cast(float, (unsigned)h << 16);
}

// ---------------------------------------------------------------------------
// fp32 -> bf16 hi/lo split, elementwise (grid-stride over float4 groups).
// ---------------------------------------------------------------------------
__global__ __launch_bounds__(256) void conv_hilo(
    const float* __restrict__ src, ush* __restrict__ hi, ush* __restrict__ lo,
    int n4)
{
    int i = blockIdx.x * blockDim.x + threadIdx.x;
    const int stride = gridDim.x * blockDim.x;
    for (; i < n4; i += stride) {
        const float4 v = ((const float4*)src)[i];
        ushort4 h, l;
        h.x = bf16_rne(v.x); l.x = bf16_rne(v.x - bf16_to_f32(h.x));
        h.y = bf16_rne(v.y); l.y = bf16_rne(v.y - bf16_to_f32(h.y));
        h.z = bf16_rne(v.z); l.z = bf16_rne(v.z - bf16_to_f32(h.z));
        h.w = bf16_rne(v.w); l.w = bf16_rne(v.w - bf16_to_f32(h.w));
        ((ushort4*)hi)[i] = h;
        ((ushort4*)lo)[i] = l;
    }
}

// ---------------------------------------------------------------------------
// C = A @ W^T + bias, bf16 hi/lo inputs, bf16x3 MFMA. (unchanged from R13)
// OMODE: 0 = bf16 [M][N]; 1 = bf16 transposed per-batch [N][SEQ]; 2 = fp32.
// ---------------------------------------------------------------------------
template<int OMODE>
__global__ __launch_bounds__(256) void gemm_pre(
    const ush* __restrict__ Ah_g, const ush* __restrict__ Al_g,
    const ush* __restrict__ Wh_g, const ush* __restrict__ Wl_g,
    const float* __restrict__ bias, void* __restrict__ Cv,
    int M, int N, int K)
{
    __shared__ __align__(16) ush Ah[4096];
    __shared__ __align__(16) ush Al[4096];
    __shared__ __align__(16) ush Wh[4096];
    __shared__ __align__(16) ush Wl[4096];

    const int tid = threadIdx.x;
    const int bm = blockIdx.x * 128;
    const int bn = blockIdx.y * 128;

    const int sr  = tid >> 1;
    const int kc0 = (tid & 1) * 2;

    const ush* Ap  = Ah_g + (size_t)(bm + sr) * K + kc0 * 8;
    const ush* Alp = Al_g + (size_t)(bm + sr) * K + kc0 * 8;
    const ush* Wp  = Wh_g + (size_t)(bn + sr) * K + kc0 * 8;
    const ush* Wlp = Wl_g + (size_t)(bn + sr) * K + kc0 * 8;

    const int lane = tid & 63;
    const int wv = tid >> 6;
    const int wm = (wv >> 1) * 64;
    const int wn = (wv & 1) * 64;
    const int fr = lane & 15;
    const int fk = lane >> 4;

    f32x4 acc[4][4];
    #pragma unroll
    for (int i = 0; i < 4; ++i)
        #pragma unroll
        for (int j = 0; j < 4; ++j)
            acc[i][j] = (f32x4){0.f, 0.f, 0.f, 0.f};

    bf16x8 rah[2], ral[2], rwh[2], rwl[2];
    #pragma unroll
    for (int s = 0; s < 2; ++s) {
        rah[s] = *(const bf16x8*)(Ap  + s * 8);
        ral[s] = *(const bf16x8*)(Alp + s * 8);
        rwh[s] = *(const bf16x8*)(Wp  + s * 8);
        rwl[s] = *(const bf16x8*)(Wlp + s * 8);
    }

    for (int k0 = 0; k0 < K; k0 += 32) {
        __syncthreads();

        #pragma unroll
        for (int s = 0; s < 2; ++s) {
            const int slot = ((kc0 + s) * 128 + sr) * 8;
            *(bf16x8*)&Ah[slot] = rah[s];
            *(bf16x8*)&Al[slot] = ral[s];
            *(bf16x8*)&Wh[slot] = rwh[s];
            *(bf16x8*)&Wl[slot] = rwl[s];
        }

        if (k0 + 32 < K) {
            #pragma unroll
            for (int s = 0; s < 2; ++s) {
                rah[s] = *(const bf16x8*)(Ap  + k0 + 32 + s * 8);
                ral[s] = *(const bf16x8*)(Alp + k0 + 32 + s * 8);
                rwh[s] = *(const bf16x8*)(Wp  + k0 + 32 + s * 8);
                rwl[s] = *(const bf16x8*)(Wlp + k0 + 32 + s * 8);
            }
        }

        __syncthreads();

        bf16x8 whf[4], wlf[4];
        #pragma unroll
        for (int nj = 0; nj < 4; ++nj) {
            whf[nj] = *(const bf16x8*)&Wh[(fk * 128 + wn + nj * 16 + fr) * 8];
            wlf[nj] = *(const bf16x8*)&Wl[(fk * 128 + wn + nj * 16 + fr) * 8];
        }
        #pragma unroll
        for (int mi = 0; mi < 4; ++mi) {
            const bf16x8 ah = *(const bf16x8*)&Ah[(fk * 128 + wm + mi * 16 + fr) * 8];
            const bf16x8 al = *(const bf16x8*)&Al[(fk * 128 + wm + mi * 16 + fr) * 8];
            #pragma unroll
            for (int nj = 0; nj < 4; ++nj) {
                acc[mi][nj] = __builtin_amdgcn_mfma_f32_16x16x32_bf16(ah, whf[nj], acc[mi][nj], 0, 0, 0);
                acc[mi][nj] = __builtin_amdgcn_mfma_f32_16x16x32_bf16(ah, wlf[nj], acc[mi][nj], 0, 0, 0);
                acc[mi][nj] = __builtin_amdgcn_mfma_f32_16x16x32_bf16(al, whf[nj], acc[mi][nj], 0, 0, 0);
            }
        }
    }

    #pragma unroll
    for (int mi = 0; mi < 4; ++mi) {
        const int row0 = bm + wm + mi * 16 + fk * 4;
        #pragma unroll
        for (int nj = 0; nj < 4; ++nj) {
            const int col = bn + wn + nj * 16 + fr;
            const float bb = bias[col];
            if (OMODE == 2) {
                float* cp = (float*)Cv + (size_t)row0 * N + col;
                #pragma unroll
                for (int j = 0; j < 4; ++j)
                    cp[(size_t)j * N] = acc[mi][nj][j] + bb;
            } else if (OMODE == 0) {
                ush* cp = (ush*)Cv + (size_t)row0 * N + col;
                #pragma unroll
                for (int j = 0; j < 4; ++j)
                    cp[(size_t)j * N] = bf16_rne(acc[mi][nj][j] + bb);
            } else {
                const int bb_ = row0 >> 11, s0 = row0 & 2047;
                ushort4 pk;
                pk.x = bf16_rne(acc[mi][nj][0] + bb);
                pk.y = bf16_rne(acc[mi][nj][1] + bb);
                pk.z = bf16_rne(acc[mi][nj][2] + bb);
                pk.w = bf16_rne(acc[mi][nj][3] + bb);
                *(ushort4*)((ush*)Cv + (size_t)bb_ * EMBED * SEQ
                            + (size_t)col * SEQ + s0) = pk;
            }
        }
    }
}

// ---------------------------------------------------------------------------
// Flash attention, bf16 in. R14: double-buffered K/V (loads before compute,
// ds_write after), defer-max softmax (THR=8), per-lane partial l sums,
// reversed qt dispatch. Core MFMA layout identical to the passing R13.
// ---------------------------------------------------------------------------
__global__ __launch_bounds__(256) void attn_mfma3(
    const ush* __restrict__ Qg, const ush* __restrict__ Kg,
    const ush* __restrict__ Vtg, ush* __restrict__ Oh, ush* __restrict__ Ol)
{
    __shared__ __align__(16) ush Ks[2][64 * 72];
    __shared__ __align__(16) ush Vs[2][64 * 72];
    __shared__ __align__(16) ush Ps[4][16 * 72];

    const int tid = threadIdx.x;
    const int bh = blockIdx.x;
    const int b = bh >> 4, h = bh & 15;
    const int qt = (SEQ / 64 - 1) - blockIdx.y;   // longest blocks first

    const int lane = tid & 63;
    const int wv = tid >> 6;
    const int fr = lane & 15;
    const int fq = lane >> 4;

    const int sr2 = tid >> 2;
    const int sc  = (tid & 3) * 16;

    const ush* kbase = Kg  + ((size_t)b * SEQ) * EMBED + h * HDIM + sc;
    const ush* vbase = Vtg + ((size_t)b * EMBED + h * HDIM + sr2) * SEQ + sc;

    // ---- Q fragments straight from global ----
    const ush* qp = Qg + ((size_t)(b * SEQ + qt * 64 + wv * 16 + fr)) * EMBED
                       + h * HDIM;
    bf16x8 qf[2];
    qf[0] = *(const bf16x8*)(qp +  0 + fq * 8);
    qf[1] = *(const bf16x8*)(qp + 32 + fq * 8);

    // ---- prologue: stage tile 0 into buffer 0 ----
    {
        const ush* kp = kbase + (size_t)sr2 * EMBED;     // k-row sr2, tile 0
        const ush* vp = vbase;                           // d-row sr2, tile 0
        bf16x8 k0 = *(const bf16x8*)kp;
        bf16x8 k1 = *(const bf16x8*)(kp + 8);
        bf16x8 v0 = *(const bf16x8*)vp;
        bf16x8 v1 = *(const bf16x8*)(vp + 8);
        *(bf16x8*)&Ks[0][sr2 * 72 + sc]     = k0;
        *(bf16x8*)&Ks[0][sr2 * 72 + sc + 8] = k1;
        *(bf16x8*)&Vs[0][sr2 * 72 + sc]     = v0;
        *(bf16x8*)&Vs[0][sr2 * 72 + sc + 8] = v1;
    }
    __syncthreads();

    float m_i[4], l_p[4];
    f32x4 o[4];
    #pragma unroll
    for (int r = 0; r < 4; ++r) { m_i[r] = -1e30f; l_p[r] = 0.f; }
    #pragma unroll
    for (int n = 0; n < 4; ++n) o[n] = (f32x4){0.f, 0.f, 0.f, 0.f};

    for (int kt = 0; kt <= qt; ++kt) {
        const int cur = kt & 1;
        const bool pf = (kt < qt);

        // ---- issue next tile's global loads early (hide under compute) ----
        bf16x8 nk0, nk1, nv0, nv1;
        if (pf) {
            const ush* kp = kbase + (size_t)((kt + 1) * 64 + sr2) * EMBED;
            const ush* vp = vbase + (kt + 1) * 64;
            nk0 = *(const bf16x8*)kp;
            nk1 = *(const bf16x8*)(kp + 8);
            nv0 = *(const bf16x8*)vp;
            nv1 = *(const bf16x8*)(vp + 8);
        }

        // ---- S = Q K^T (8 MFMA) ----
        f32x4 sc4[4];
        #pragma unroll
        for (int n = 0; n < 4; ++n) sc4[n] = (f32x4){0.f, 0.f, 0.f, 0.f};
        #pragma unroll
        for (int kc = 0; kc < 2; ++kc)
            #pragma unroll
            for (int n = 0; n < 4; ++n) {
                const bf16x8 kf = *(const bf16x8*)&Ks[cur][(n * 16 + fr) * 72 + kc * 32 + fq * 8];
                sc4[n] = __builtin_amdgcn_mfma_f32_16x16x32_bf16(qf[kc], kf, sc4[n], 0, 0, 0);
            }

        // ---- scale + causal mask ----
        const bool diag = (kt == qt);
        float t[4][4];
        #pragma unroll
        for (int n = 0; n < 4; ++n)
            #pragma unroll
            for (int r = 0; r < 4; ++r) {
                float s = sc4[n][r] * 0.125f;
                if (diag && (n * 16 + fr > wv * 16 + fq * 4 + r)) s = -1e30f;
                t[n][r] = s;
            }

        // ---- defer-max online softmax ----
        float pmax[4];
        #pragma unroll
        for (int r = 0; r < 4; ++r)
            pmax[r] = fmaxf(fmaxf(t[0][r], t[1][r]), fmaxf(t[2][r], t[3][r]));

        const bool ok = (pmax[0] <= m_i[0] + 8.f) & (pmax[1] <= m_i[1] + 8.f)
                      & (pmax[2] <= m_i[2] + 8.f) & (pmax[3] <= m_i[3] + 8.f);
        if (!__all(ok)) {
            #pragma unroll
            for (int r = 0; r < 4; ++r) {
                float mx = pmax[r];
                mx = fmaxf(mx, __shfl_xor(mx, 1));
                mx = fmaxf(mx, __shfl_xor(mx, 2));
                mx = fmaxf(mx, __shfl_xor(mx, 4));
                mx = fmaxf(mx, __shfl_xor(mx, 8));
                const float mnew = fmaxf(m_i[r], mx);
                const float corr = __expf(m_i[r] - mnew);
                l_p[r] *= corr;
                o[0][r] *= corr; o[1][r] *= corr; o[2][r] *= corr; o[3][r] *= corr;
                m_i[r] = mnew;
            }
        }
        #pragma unroll
        for (int r = 0; r < 4; ++r) {
            float ps = 0.f;
            #pragma unroll
            for (int n = 0; n < 4; ++n) {
                const float p = __expf(t[n][r] - m_i[r]);
                Ps[wv][(fq * 4 + r) * 72 + n * 16 + fr] = bf16_rne(p);
                ps += p;
            }
            l_p[r] += ps;               // per-lane partial; reduced in epilogue
        }

        // ---- O += P V (8 MFMA) ----
        #pragma unroll
        for (int kc = 0; kc < 2; ++kc) {
            const bf16x8 pfg = *(const bf16x8*)&Ps[wv][fr * 72 + kc * 32 + fq * 8];
            #pragma unroll
            for (int n = 0; n < 4; ++n) {
                const bf16x8 vf = *(const bf16x8*)&Vs[cur][(n * 16 + fr) * 72 + kc * 32 + fq * 8];
                o[n] = __builtin_amdgcn_mfma_f32_16x16x32_bf16(pfg, vf, o[n], 0, 0, 0);
            }
        }

        // ---- write staged regs into the other buffer, then barrier ----
        if (pf) {
            const int nxt = cur ^ 1;
            *(bf16x8*)&Ks[nxt][sr2 * 72 + sc]     = nk0;
            *(bf16x8*)&Ks[nxt][sr2 * 72 + sc + 8] = nk1;
            *(bf16x8*)&Vs[nxt][sr2 * 72 + sc]     = nv0;
            *(bf16x8*)&Vs[nxt][sr2 * 72 + sc + 8] = nv1;
            __syncthreads();
        }
    }

    // ---- epilogue: reduce l across the 16-lane row group, write ctx ----
    #pragma unroll
    for (int r = 0; r < 4; ++r) {
        float l = l_p[r];
        l += __shfl_xor(l, 1);
        l += __shfl_xor(l, 2);
        l += __shfl_xor(l, 4);
        l += __shfl_xor(l, 8);
        const float inv = 1.f / l;
        const size_t rowoff = ((size_t)(b * SEQ + qt * 64 + wv * 16 + fq * 4 + r)) * EMBED
                              + h * HDIM;
        #pragma unroll
        for (int n = 0; n < 4; ++n) {
            const float val = o[n][r] * inv;
            const ush hv = bf16_rne(val);
            Oh[rowoff + n * 16 + fr] = hv;
            Ol[rowoff + n * 16 + fr] = bf16_rne(val - bf16_to_f32(hv));
        }
    }
}

// ---------------------------------------------------------------------------
extern "C" void kernel_launch(void* const* d_in, const int* in_sizes, int n_in,
                              void* d_out, int out_size, void* d_ws, size_t ws_size,
                              hipStream_t stream)
{
    const float* x  = (const float*)d_in[0];
    const float* Wq = (const float*)d_in[1];
    const float* bq = (const float*)d_in[2];
    const float* Wk = (const float*)d_in[3];
    const float* bk = (const float*)d_in[4];
    const float* Wv = (const float*)d_in[5];
    const float* bv = (const float*)d_in[6];
    const float* Wo = (const float*)d_in[7];
    const float* bo = (const float*)d_in[8];
    float* out = (float*)d_out;

    const size_t XN = (size_t)MROWS * EMBED;
    const size_t WN = (size_t)EMBED * EMBED;
    if (ws_size < 2 * XN * sizeof(float)) return;

    ush* wsu  = (ush*)d_ws;
    ush* qb   = wsu;
    ush* kb   = wsu + XN;
    ush* x_hi = wsu + 2 * XN;
    ush* x_lo = wsu + 3 * XN;
    ush* ctx_hi = qb;
    ush* ctx_lo = x_hi;
    ush* wo_h = x_lo;
    ush* wo_l = x_lo + WN;

    ush* dov  = (ush*)d_out;
    ush* vt   = dov;
    ush* w_hi = dov + XN;
    ush* w_lo = dov + XN + WN;

    dim3 gg(MROWS / 128, EMBED / 128);

    conv_hilo<<<2048, 256, 0, stream>>>(x, x_hi, x_lo, (int)(XN / 4));

    conv_hilo<<<1024, 256, 0, stream>>>(Wq, w_hi, w_lo, (int)(WN / 4));
    gemm_pre<0><<<gg, 256, 0, stream>>>(x_hi, x_lo, w_hi, w_lo, bq, qb, MROWS, EMBED, EMBED);

    conv_hilo<<<1024, 256, 0, stream>>>(Wk, w_hi, w_lo, (int)(WN / 4));
    gemm_pre<0><<<gg, 256, 0, stream>>>(x_hi, x_lo, w_hi, w_lo, bk, kb, MROWS, EMBED, EMBED);

    conv_hilo<<<1024, 256, 0, stream>>>(Wv, w_hi, w_lo, (int)(WN / 4));
    gemm_pre<1><<<gg, 256, 0, stream>>>(x_hi, x_lo, w_hi, w_lo, bv, vt, MROWS, EMBED, EMBED);

    attn_mfma3<<<dim3(NHEADS * 2, SEQ / 64), 256, 0, stream>>>(qb, kb, vt, ctx_hi, ctx_lo);

    conv_hilo<<<1024, 256, 0, stream>>>(Wo, wo_h, wo_l, (int)(WN / 4));
    gemm_pre<2><<<gg, 256, 0, stream>>>(ctx_hi, ctx_lo, wo_h, wo_l, bo, out, MROWS, EMBED, EMBED);
}